// Round 6
// baseline (423.460 us; speedup 1.0000x reference)
//
#include <hip/hip_runtime.h>
#include <stdint.h>

#define T_SEQ 2048
#define DDIM  1024
#define BATCH 8

using f32x4 = __attribute__((ext_vector_type(4))) float;
using half8 = __attribute__((ext_vector_type(8))) _Float16;
using half4 = __attribute__((ext_vector_type(4))) _Float16;

// async global->LDS, 16B/lane; LDS dest = wave-uniform base + lane*16
__device__ __forceinline__ void gl_lds16(const _Float16* g, _Float16* l) {
  __builtin_amdgcn_global_load_lds((const __attribute__((address_space(1))) void*)g,
                                   (__attribute__((address_space(3))) void*)l,
                                   16, 0, 0);
}

// ---------------------------------------------------------------- converts
__global__ __launch_bounds__(256) void cvt_all(
    const float* __restrict__ Wq, const float* __restrict__ Wk,
    const float* __restrict__ Wv, const float* __restrict__ Wg,
    const float* __restrict__ x, _Float16* __restrict__ Wb,
    _Float16* __restrict__ Wgs, _Float16* __restrict__ x16) {
  const size_t i = ((size_t)blockIdx.x * 256 + threadIdx.x) * 8;
  const float* s; _Float16* d; size_t off;
  if (i < (size_t)(1 << 20))      { s = Wq; d = Wb;             off = i; }
  else if (i < (size_t)(2 << 20)) { s = Wk; d = Wb + (1 << 20); off = i - (1 << 20); }
  else if (i < (size_t)(3 << 20)) { s = Wv; d = Wb + (2 << 20); off = i - (2 << 20); }
  else if (i < (size_t)(4 << 20)) { s = Wg; d = Wgs;            off = i - (3 << 20); }
  else                            { s = x;  d = x16;            off = i - (4 << 20); }
  float4 a = *(const float4*)(s + off);
  float4 b = *(const float4*)(s + off + 4);
  half8 h;
  h[0] = (_Float16)a.x; h[1] = (_Float16)a.y; h[2] = (_Float16)a.z; h[3] = (_Float16)a.w;
  h[4] = (_Float16)b.x; h[5] = (_Float16)b.y; h[6] = (_Float16)b.z; h[7] = (_Float16)b.w;
  *(half8*)(d + off) = h;
}

// WqT[d][e] = (f16)Wq[e][d]  (64x64 LDS-tiled transpose)
__global__ __launch_bounds__(256) void trans_wq(const float* __restrict__ Wq,
                                                _Float16* __restrict__ WqT) {
  __shared__ _Float16 t[64][65];
  const int bx = blockIdx.x, by = blockIdx.y;
  const int c = threadIdx.x & 63, r = threadIdx.x >> 6;
#pragma unroll
  for (int rr = 0; rr < 16; ++rr) {
    const int el = r * 16 + rr;
    t[c][el] = (_Float16)Wq[(size_t)(by * 64 + el) * DDIM + bx * 64 + c];
  }
  __syncthreads();
#pragma unroll
  for (int rr = 0; rr < 16; ++rr) {
    const int dl = r * 16 + rr;
    WqT[(size_t)(bx * 64 + dl) * DDIM + by * 64 + c] = t[dl][c];
  }
}

// bgq[f] = sum_e Wg[f][e]*bq[e] + bg[f]
__global__ __launch_bounds__(256) void bgq_kernel(const float* __restrict__ Wg,
                                                  const float* __restrict__ bq,
                                                  const float* __restrict__ bg,
                                                  float* __restrict__ bgq) {
  const int f = blockIdx.x, tid = threadIdx.x;
  float4 wv = *(const float4*)&Wg[(size_t)f * DDIM + tid * 4];
  float4 bv = *(const float4*)&bq[tid * 4];
  float s = wv.x * bv.x + wv.y * bv.y + wv.z * bv.z + wv.w * bv.w;
#pragma unroll
  for (int off = 32; off > 0; off >>= 1) s += __shfl_xor(s, off);
  __shared__ float red[4];
  if ((tid & 63) == 0) red[tid >> 6] = s;
  __syncthreads();
  if (tid == 0) bgq[f] = red[0] + red[1] + red[2] + red[3] + bg[f];
}

// ---------------------------------------------------------------- 256^2 8-phase GEMM core
// Two barriers/phase (template); depth-3 half-tile pipeline, vmcnt(6)@p4/p8;
// XOR swizzle granule^=(row&7) via inverse-swizzled gl_lds source; setprio;
// ks-outer MFMA (8 independent then 8 dependent).
#define STG(SM, sb, sh, st)                                                        \
  { const _Float16* g_ = (SM) ? Bg : Ag;                                           \
    const size_t r0_ = (SM) ? brow0 : arow0, r1_ = (SM) ? brow1 : arow1;           \
    const size_t h_  = (sh) ? ((SM) ? bh128 : ah128) : 0;                          \
    _Float16* l_ = ((SM) ? Bs : As) + (((sb) * 2 + (sh)) << 13);                   \
    gl_lds16(g_ + r0_ + h_ + (size_t)(st) * 64 + sg0 * 8, l_ + lo0);               \
    gl_lds16(g_ + r1_ + h_ + (size_t)(st) * 64 + sg1 * 8, l_ + lo1); }

#define PH(cb, mh, nh, RA, VW, ...)                                                \
  {                                                                                \
    if (RA) {                                                                      \
      const _Float16* ah_ = As + (((cb) * 2 + (mh)) << 13);                        \
      _Pragma("unroll") for (int mi = 0; mi < 4; ++mi)                             \
        _Pragma("unroll") for (int ks = 0; ks < 2; ++ks)                           \
          ar[mi][ks] = *(const half8*)(ah_ + aoff[mi] + koff[ks]);                 \
    }                                                                              \
    { const _Float16* bh_ = Bs + (((cb) * 2 + (nh)) << 13);                        \
      _Pragma("unroll") for (int ni = 0; ni < 2; ++ni)                             \
        _Pragma("unroll") for (int ks = 0; ks < 2; ++ks)                           \
          br[ni][ks] = *(const half8*)(bh_ + boff[ni] + koff[ks]); }               \
    __VA_ARGS__;                                                                   \
    __builtin_amdgcn_s_barrier();                                                  \
    asm volatile("s_waitcnt lgkmcnt(0)" ::: "memory");                             \
    __builtin_amdgcn_sched_barrier(0);                                             \
    __builtin_amdgcn_s_setprio(1);                                                 \
    _Pragma("unroll") for (int ks = 0; ks < 2; ++ks)                               \
      _Pragma("unroll") for (int mi = 0; mi < 4; ++mi)                             \
        _Pragma("unroll") for (int ni = 0; ni < 2; ++ni)                           \
          acc[(mh) * 4 + mi][(nh) * 2 + ni] =                                      \
              __builtin_amdgcn_mfma_f32_16x16x32_f16(                              \
                  ar[mi][ks], br[ni][ks], acc[(mh) * 4 + mi][(nh) * 2 + ni],       \
                  0, 0, 0);                                                        \
    __builtin_amdgcn_s_setprio(0);                                                 \
    if (VW) { asm volatile("s_waitcnt vmcnt(6)" ::: "memory");                     \
              __builtin_amdgcn_sched_barrier(0); }                                 \
    __builtin_amdgcn_s_barrier();                                                  \
    asm volatile("" ::: "memory");                                                 \
  }

__device__ __forceinline__ void gemm8p(const _Float16* __restrict__ Ag,
                                       const _Float16* __restrict__ Bg,
                                       int lda, int ldb, int K,
                                       f32x4 acc[8][4],
                                       _Float16* As, _Float16* Bs) {
  const int tid = threadIdx.x;
  const int lane = tid & 63;
  const int w = tid >> 6;
  const int wm = w >> 2, wn = w & 3;
  const int lr = lane & 15, kl = lane >> 4;

  int aoff[4], boff[2], koff[2];
#pragma unroll
  for (int mi = 0; mi < 4; ++mi) aoff[mi] = (wm * 64 + mi * 16 + lr) * 64;
#pragma unroll
  for (int ni = 0; ni < 2; ++ni) boff[ni] = (wn * 32 + ni * 16 + lr) * 64;
#pragma unroll
  for (int ks = 0; ks < 2; ++ks) koff[ks] = ((ks * 4 + kl) ^ (lr & 7)) * 8;

  const int s0 = (w * 2 + 0) * 64 + lane, s1 = (w * 2 + 1) * 64 + lane;
  const int srow0 = s0 >> 3, srow1 = s1 >> 3;
  const int sg0 = (s0 & 7) ^ (srow0 & 7), sg1 = (s1 & 7) ^ (srow1 & 7);
  const int lo0 = (w * 2 + 0) * 512, lo1 = (w * 2 + 1) * 512;
  const size_t arow0 = (size_t)srow0 * lda, arow1 = (size_t)srow1 * lda;
  const size_t brow0 = (size_t)srow0 * ldb, brow1 = (size_t)srow1 * ldb;
  const size_t ah128 = (size_t)128 * lda, bh128 = (size_t)128 * ldb;

  const int NT = K >> 6, NITER = NT >> 1, TM = NT - 1;
  half8 ar[4][2], br[2][2];

  // prologue: t0 all 4 halves + t1.Ah0, t1.Bh0, t1.Ah1 (7 halves, 14 loads/lane)
  STG(0, 0, 0, 0); STG(1, 0, 0, 0);
  STG(0, 0, 1, 0); STG(1, 0, 1, 0);
  STG(0, 1, 0, 1); STG(1, 1, 0, 1);
  STG(0, 1, 1, 1);
  asm volatile("s_waitcnt vmcnt(6)" ::: "memory");  // drains t0's 4 halves
  __builtin_amdgcn_sched_barrier(0);
  __builtin_amdgcn_s_barrier();
  asm volatile("" ::: "memory");

  for (int it = 0; it < NITER; ++it) {
    const int tb = 2 * it + 1;
    const int tc = (2 * it + 2) & TM;  // wrap: harmless reload at the tail
    const int td = (2 * it + 3) & TM;
    // phases 1-4: compute buf0 (tile 2it); 3 halves in flight, vmcnt(6)@p4
    PH(0, 0, 0, 1, 0, STG(1, 1, 1, tb))                     // tb.B.h1 -> buf1
    PH(0, 0, 1, 0, 0, STG(0, 0, 0, tc))                     // tc.A.h0 -> buf0
    PH(0, 1, 0, 1, 0, )                                     // (no stage)
    PH(0, 1, 1, 0, 1, STG(1, 0, 0, tc); STG(0, 0, 1, tc))   // tc.B.h0,A.h1 ; vmcnt(6)->tb landed
    // phases 5-8: compute buf1 (tile 2it+1)
    PH(1, 0, 0, 1, 0, STG(1, 0, 1, tc))                     // tc.B.h1 -> buf0
    PH(1, 0, 1, 0, 0, STG(0, 1, 0, td))                     // td.A.h0 -> buf1
    PH(1, 1, 0, 1, 0, )                                     // (no stage)
    PH(1, 1, 1, 0, 1, STG(1, 1, 0, td); STG(0, 1, 1, td))   // td.B.h0,A.h1 ; vmcnt(6)->tc landed
  }
  asm volatile("s_waitcnt vmcnt(0)" ::: "memory");  // drain wrapped stages
}

#define GEMM_PROLOGUE()                                              \
  __shared__ __align__(16) unsigned char SMEM[131072];               \
  _Float16* As = (_Float16*)SMEM;                                    \
  _Float16* Bs = (_Float16*)(SMEM + 65536);                          \
  f32x4 acc[8][4];                                                   \
  _Pragma("unroll") for (int i_ = 0; i_ < 8; ++i_)                   \
      _Pragma("unroll") for (int j_ = 0; j_ < 4; ++j_)               \
          acc[i_][j_] = (f32x4){0.f, 0.f, 0.f, 0.f};

#define EPI_IDX()                                                    \
  const int tid = threadIdx.x, lane = tid & 63, w = tid >> 6;        \
  const int wm = w >> 2, wn = w & 3, lr = lane & 15, kl = lane >> 4; \
  (void)tid; (void)lane;

// ---------------------------------------------------------------- kernels
// Wgq[f][d] = (f16) sum_e Wgs[f][e] * WqT[d][e]   (16 blocks; epilogue perf moot)
__global__ __launch_bounds__(512, 2) void wgq_kernel(
    const _Float16* __restrict__ Wgs, const _Float16* __restrict__ WqT,
    _Float16* __restrict__ Wgq) {
  GEMM_PROLOGUE();
  const int m0 = blockIdx.x * 256;
  const int n0 = blockIdx.y * 256;
  gemm8p(Wgs + (size_t)m0 * DDIM, WqT + (size_t)n0 * DDIM, DDIM, DDIM, DDIM,
         acc, As, Bs);
  EPI_IDX();
#pragma unroll
  for (int a = 0; a < 8; ++a) {
    const int row0 = m0 + (a >> 2) * 128 + wm * 64 + (a & 3) * 16 + kl * 4;
#pragma unroll
    for (int bi = 0; bi < 4; ++bi) {
      const int col = n0 + (bi >> 1) * 128 + wn * 32 + (bi & 1) * 16 + lr;
#pragma unroll
      for (int r = 0; r < 4; ++r)
        Wgq[(size_t)(row0 + r) * DDIM + col] = (_Float16)acc[a][bi][r];
    }
  }
}

// [Q|K''|V^T|gate] = x16 @ [Wq|Wk|Wv|Wgq]^T ; 4 regions, grid 64x16
__global__ __launch_bounds__(512, 2) void proj_kernel(
    const _Float16* __restrict__ x16, const _Float16* __restrict__ Wb,
    _Float16* __restrict__ Qb, _Float16* __restrict__ Kb, _Float16* __restrict__ Vt,
    float* __restrict__ gate_out,
    const float* __restrict__ bq, const float* __restrict__ bk,
    const float* __restrict__ bv, const float* __restrict__ bgq,
    const float* __restrict__ alpha_p, const float* __restrict__ attn_bias) {
  GEMM_PROLOGUE();
  const int m0 = blockIdx.x * 256;
  const int n0 = blockIdx.y * 256;
  gemm8p(x16 + (size_t)m0 * DDIM, Wb + (size_t)n0 * DDIM, DDIM, DDIM, DDIM,
         acc, As, Bs);
  EPI_IDX();
  const int region = blockIdx.y >> 2;  // 0=Q 1=K 2=V 3=gate
  const float alsc = alpha_p[0] * 0.03125f;  // alpha / sqrt(1024)
  __syncthreads();  // fence in-flight wrapped gl_lds before LDS reuse
  if (region == 2) {
    // V: frag rows are s-contiguous in Vt -> direct half4 stores
#pragma unroll
    for (int a = 0; a < 8; ++a) {
      const int row0 = m0 + (a >> 2) * 128 + wm * 64 + (a & 3) * 16 + kl * 4;
#pragma unroll
      for (int bi = 0; bi < 4; ++bi) {
        const int col = n0 + (bi >> 1) * 128 + wn * 32 + (bi & 1) * 16 + lr;
        const int d = col - 2048;
        const float bias = bv[d];
        const int bidx = row0 >> 11;
        const int sr = row0 & (T_SEQ - 1);
        half4 p;
#pragma unroll
        for (int r = 0; r < 4; ++r) p[r] = (_Float16)(acc[a][bi][r] + bias);
        *(half4*)&Vt[((size_t)bidx * DDIM + d) * T_SEQ + sr] = p;
      }
    }
  } else if (region == 3) {
    // gate = sigmoid(acc + bgq), fp32 -> out (parked for pv), LDS transpose
    float* sc = (float*)(SMEM + (size_t)w * 9216);
#pragma unroll
    for (int mh = 0; mh < 2; ++mh)
#pragma unroll
      for (int nh = 0; nh < 2; ++nh) {
#pragma unroll
        for (int mi = 0; mi < 4; ++mi)
#pragma unroll
          for (int ni = 0; ni < 2; ++ni) {
            const int col_l = ni * 16 + lr;
            const float b = bgq[n0 + nh * 128 + wn * 32 + col_l - 3072];
            f32x4 v = acc[mh * 4 + mi][nh * 2 + ni];
#pragma unroll
            for (int r = 0; r < 4; ++r)
              sc[(mi * 16 + kl * 4 + r) * 36 + col_l] =
                  1.0f / (1.0f + __expf(-(v[r] + b)));
          }
#pragma unroll
        for (int p = 0; p < 8; ++p) {
          const int row = p * 8 + (lane >> 3);
          const int c4 = (lane & 7) * 4;
          f32x4 v = *(const f32x4*)&sc[row * 36 + c4];
          *(f32x4*)&gate_out[(size_t)(m0 + mh * 128 + wm * 64 + row) * DDIM +
                             n0 + nh * 128 + wn * 32 + c4 - 3072] = v;
        }
      }
  } else {
    // Q/K: per-wave LDS transpose (stride 56 f16), coalesced half8 stores
    _Float16* sc = (_Float16*)(SMEM + (size_t)w * 7168);
    _Float16* dst = (region == 0) ? Qb : Kb;
    const int coff = (region == 1) ? 1024 : 0;
#pragma unroll
    for (int mh = 0; mh < 2; ++mh)
#pragma unroll
      for (int nh = 0; nh < 2; ++nh) {
#pragma unroll
        for (int mi = 0; mi < 4; ++mi) {
          const int row_l = mi * 16 + kl * 4;
          const int s0g = (m0 + mh * 128 + wm * 64 + row_l) & (T_SEQ - 1);
#pragma unroll
          for (int ni = 0; ni < 2; ++ni) {
            const int col_l = ni * 16 + lr;
            const int colg = n0 + nh * 128 + wn * 32 + col_l;
            f32x4 v = acc[mh * 4 + mi][nh * 2 + ni];
            if (region == 0) {
              const float b = bq[colg];
#pragma unroll
              for (int r = 0; r < 4; ++r)
                sc[(row_l + r) * 56 + col_l] = (_Float16)(v[r] + b);
            } else {
              const int d = colg - 1024;
              const float b = bk[d];
              float4 ab = *(const float4*)&attn_bias[(size_t)d * T_SEQ + s0g];
              sc[(row_l + 0) * 56 + col_l] = (_Float16)((v[0] + b) * alsc + ab.x);
              sc[(row_l + 1) * 56 + col_l] = (_Float16)((v[1] + b) * alsc + ab.y);
              sc[(row_l + 2) * 56 + col_l] = (_Float16)((v[2] + b) * alsc + ab.z);
              sc[(row_l + 3) * 56 + col_l] = (_Float16)((v[3] + b) * alsc + ab.w);
            }
          }
        }
#pragma unroll
        for (int p = 0; p < 4; ++p) {
          const int row = p * 16 + (lane >> 2);
          const int c8 = (lane & 3) * 8;
          half8 hv = *(const half8*)&sc[row * 56 + c8];
          *(half8*)&dst[(size_t)(m0 + mh * 128 + wm * 64 + row) * DDIM +
                        n0 + nh * 128 + wn * 32 + c8 - coff] = hv;
        }
      }
  }
}

__global__ __launch_bounds__(512, 2) void scores_kernel(
    const _Float16* __restrict__ Qb, const _Float16* __restrict__ Kb,
    float* __restrict__ w_out) {
  GEMM_PROLOGUE();
  const int b = blockIdx.z;
  const int m0 = blockIdx.x * 256;
  const int n0 = blockIdx.y * 256;
  gemm8p(Qb + ((size_t)b * T_SEQ + m0) * DDIM,
         Kb + ((size_t)b * T_SEQ + n0) * DDIM, DDIM, DDIM, DDIM,
         acc, As, Bs);
  EPI_IDX();
  __syncthreads();
  float* wp = w_out + (size_t)b * T_SEQ * T_SEQ;
  float* sc = (float*)(SMEM + (size_t)w * 9216);
#pragma unroll
  for (int mh = 0; mh < 2; ++mh)
#pragma unroll
    for (int nh = 0; nh < 2; ++nh) {
#pragma unroll
      for (int mi = 0; mi < 4; ++mi)
#pragma unroll
        for (int ni = 0; ni < 2; ++ni) {
          f32x4 v = acc[mh * 4 + mi][nh * 2 + ni];
#pragma unroll
          for (int r = 0; r < 4; ++r)
            sc[(mi * 16 + kl * 4 + r) * 36 + ni * 16 + lr] = v[r];
        }
#pragma unroll
      for (int p = 0; p < 8; ++p) {
        const int row = p * 8 + (lane >> 3);
        const int c4 = (lane & 7) * 4;
        f32x4 v = *(const f32x4*)&sc[row * 36 + c4];
        *(f32x4*)&wp[(size_t)(m0 + mh * 128 + wm * 64 + row) * T_SEQ +
                     n0 + nh * 128 + wn * 32 + c4] = v;
      }
    }
}

// in-place fp32 row softmax over 2048, plus f16 copy for the PV GEMM
__global__ __launch_bounds__(256) void softmax_kernel(float* __restrict__ wmat,
                                                      _Float16* __restrict__ P16) {
  float* row = wmat + (size_t)blockIdx.x * T_SEQ;
  const int tid = threadIdx.x;
  float4 v0 = *(float4*)(row + tid * 4);
  float4 v1 = *(float4*)(row + 1024 + tid * 4);
  float m = fmaxf(fmaxf(fmaxf(v0.x, v0.y), fmaxf(v0.z, v0.w)),
                  fmaxf(fmaxf(v1.x, v1.y), fmaxf(v1.z, v1.w)));
#pragma unroll
  for (int off = 32; off > 0; off >>= 1) m = fmaxf(m, __shfl_xor(m, off));
  __shared__ float red[8];
  const int wv = tid >> 6, ln = tid & 63;
  if (ln == 0) red[wv] = m;
  __syncthreads();
  m = fmaxf(fmaxf(red[0], red[1]), fmaxf(red[2], red[3]));
  v0.x = __expf(v0.x - m); v0.y = __expf(v0.y - m);
  v0.z = __expf(v0.z - m); v0.w = __expf(v0.w - m);
  v1.x = __expf(v1.x - m); v1.y = __expf(v1.y - m);
  v1.z = __expf(v1.z - m); v1.w = __expf(v1.w - m);
  float s = v0.x + v0.y + v0.z + v0.w + v1.x + v1.y + v1.z + v1.w;
#pragma unroll
  for (int off = 32; off > 0; off >>= 1) s += __shfl_xor(s, off);
  if (ln == 0) red[4 + wv] = s;
  __syncthreads();
  const float inv = 1.0f / (red[4] + red[5] + red[6] + red[7]);
  v0.x *= inv; v0.y *= inv; v0.z *= inv; v0.w *= inv;
  v1.x *= inv; v1.y *= inv; v1.z *= inv; v1.w *= inv;
  *(float4*)(row + tid * 4) = v0;
  *(float4*)(row + 1024 + tid * 4) = v1;
  _Float16* prow = P16 + (size_t)blockIdx.x * T_SEQ;
  half4 h0, h1;
  h0[0] = (_Float16)v0.x; h0[1] = (_Float16)v0.y; h0[2] = (_Float16)v0.z; h0[3] = (_Float16)v0.w;
  h1[0] = (_Float16)v1.x; h1[1] = (_Float16)v1.y; h1[2] = (_Float16)v1.z; h1[3] = (_Float16)v1.w;
  *(half4*)(prow + tid * 4) = h0;
  *(half4*)(prow + 1024 + tid * 4) = h1;
}

// attn_output[b] = (P16_b @ V_b) * gate ; gate parked in `out` (exact aliasing).
__global__ __launch_bounds__(512, 2) void pv_kernel(
    const _Float16* __restrict__ P16, const _Float16* __restrict__ Vt,
    float* __restrict__ out) {
  GEMM_PROLOGUE();
  const int b = blockIdx.z;
  const int m0 = blockIdx.x * 256;
  const int n0 = blockIdx.y * 256;
  gemm8p(P16 + ((size_t)b * T_SEQ + m0) * T_SEQ,
         Vt + (size_t)b * DDIM * T_SEQ + (size_t)n0 * T_SEQ,
         T_SEQ, T_SEQ, T_SEQ, acc, As, Bs);
  EPI_IDX();
  __syncthreads();
  float* sc = (float*)(SMEM + (size_t)w * 9216);
#pragma unroll
  for (int mh = 0; mh < 2; ++mh)
#pragma unroll
    for (int nh = 0; nh < 2; ++nh) {
#pragma unroll
      for (int mi = 0; mi < 4; ++mi)
#pragma unroll
        for (int ni = 0; ni < 2; ++ni) {
          f32x4 v = acc[mh * 4 + mi][nh * 2 + ni];
#pragma unroll
          for (int r = 0; r < 4; ++r)
            sc[(mi * 16 + kl * 4 + r) * 36 + ni * 16 + lr] = v[r];
        }
#pragma unroll
      for (int p = 0; p < 8; ++p) {
        const int row = p * 8 + (lane >> 3);
        const int c4 = (lane & 7) * 4;
        f32x4 v = *(const f32x4*)&sc[row * 36 + c4];
        float* op = &out[(size_t)((size_t)b * T_SEQ + m0 + mh * 128 + wm * 64 + row) * DDIM +
                         n0 + nh * 128 + wn * 32 + c4];
        f32x4 g = *(const f32x4*)op;  // gate parked here by proj region 3
        *(f32x4*)op = v * g;
      }
    }
}

// ---------------------------------------------------------------- launch
extern "C" void kernel_launch(void* const* d_in, const int* in_sizes, int n_in,
                              void* d_out, int out_size, void* d_ws, size_t ws_size,
                              hipStream_t stream) {
  const float* x         = (const float*)d_in[0];
  const float* Wq        = (const float*)d_in[1];
  const float* bq        = (const float*)d_in[2];
  const float* Wk        = (const float*)d_in[3];
  const float* bk        = (const float*)d_in[4];
  const float* Wv        = (const float*)d_in[5];
  const float* bv        = (const float*)d_in[6];
  const float* Wg        = (const float*)d_in[7];
  const float* bg        = (const float*)d_in[8];
  const float* alpha     = (const float*)d_in[9];
  const float* attn_bias = (const float*)d_in[10];

  float* out   = (float*)d_out;
  float* out_w = out + (size_t)BATCH * T_SEQ * DDIM;  // attn_weights region

  // ws (f16 units): Wb[0,4M) = [Wq|Wk|Wv|Wgq] | Qb[4M,20M) | Kb[20M,36M) | Vt[36M,52M)
  _Float16* Wb  = (_Float16*)d_ws;
  _Float16* Qb  = Wb + ((size_t)4 << 20);
  _Float16* Kb  = Qb + ((size_t)16 << 20);
  _Float16* Vt  = Kb + ((size_t)16 << 20);
  _Float16* P16 = Qb;  // 64 MiB alias (Qb+Kb dead after scores)
  // scratch parked in the attn_weights output region (dead before scores writes it)
  _Float16* x16 = (_Float16*)out_w;                       // [0, 8M) floats
  _Float16* Wgs = (_Float16*)(out_w + ((size_t)9 << 20)); // Wg f16
  _Float16* WqT = (_Float16*)(out_w + ((size_t)10 << 20));// Wq^T f16
  float*    bgq = out_w + ((size_t)11 << 20);             // folded gate bias
  _Float16* Wgq = Wb + ((size_t)3 << 20);                 // region 3 of Wb

  cvt_all<<<10240, 256, 0, stream>>>(Wq, Wk, Wv, Wg, x, Wb, Wgs, x16);
  trans_wq<<<dim3(16, 16), 256, 0, stream>>>(Wq, WqT);
  bgq_kernel<<<1024, 256, 0, stream>>>(Wg, bq, bg, bgq);
  wgq_kernel<<<dim3(4, 4), 512, 0, stream>>>(Wgs, WqT, Wgq);
  proj_kernel<<<dim3(64, 16), 512, 0, stream>>>(x16, Wb, Qb, Kb, Vt, out,
                                                bq, bk, bv, bgq, alpha, attn_bias);
  scores_kernel<<<dim3(8, 8, 8), 512, 0, stream>>>(Qb, Kb, out_w);
  softmax_kernel<<<16384, 256, 0, stream>>>(out_w, P16);
  pv_kernel<<<dim3(8, 4, 8), 512, 0, stream>>>(P16, Vt, out);
}

// Round 7
// 381.468 us; speedup vs baseline: 1.1101x; 1.1101x over previous
//
#include <hip/hip_runtime.h>
#include <stdint.h>

#define T_SEQ 2048
#define DDIM  1024
#define BATCH 8

using f32x4 = __attribute__((ext_vector_type(4))) float;
using half8 = __attribute__((ext_vector_type(8))) _Float16;
using half4 = __attribute__((ext_vector_type(4))) _Float16;

// async global->LDS, 16B/lane; LDS dest = wave-uniform base + lane*16
__device__ __forceinline__ void gl_lds16(const _Float16* g, _Float16* l) {
  __builtin_amdgcn_global_load_lds((const __attribute__((address_space(1))) void*)g,
                                   (__attribute__((address_space(3))) void*)l,
                                   16, 0, 0);
}

// ---------------------------------------------------------------- converts
__global__ __launch_bounds__(256) void cvt_all(
    const float* __restrict__ Wq, const float* __restrict__ Wk,
    const float* __restrict__ Wv, const float* __restrict__ Wg,
    const float* __restrict__ x, _Float16* __restrict__ Wb,
    _Float16* __restrict__ x16) {
  const size_t i = ((size_t)blockIdx.x * 256 + threadIdx.x) * 8;
  const float* s; _Float16* d; size_t off;
  if (i < (size_t)(1 << 20))      { s = Wq; d = Wb;             off = i; }
  else if (i < (size_t)(2 << 20)) { s = Wk; d = Wb + (1 << 20); off = i - (1 << 20); }
  else if (i < (size_t)(3 << 20)) { s = Wv; d = Wb + (2 << 20); off = i - (2 << 20); }
  else if (i < (size_t)(4 << 20)) { s = Wg; d = Wb + (3 << 20); off = i - (3 << 20); }
  else                            { s = x;  d = x16;            off = i - (4 << 20); }
  float4 a = *(const float4*)(s + off);
  float4 b = *(const float4*)(s + off + 4);
  half8 h;
  h[0] = (_Float16)a.x; h[1] = (_Float16)a.y; h[2] = (_Float16)a.z; h[3] = (_Float16)a.w;
  h[4] = (_Float16)b.x; h[5] = (_Float16)b.y; h[6] = (_Float16)b.z; h[7] = (_Float16)b.w;
  *(half8*)(d + off) = h;
}

// ---------------------------------------------------------------- 256^2 8-phase GEMM core
// ks-pipelined: per phase {R1 || M8(ks0) || R0(next) || M8(ks1)}, counted lgkm,
// one barrier/phase; quadrant order (0,1),(0,0),(1,0),(1,1) -> A read once,
// B re-read once (28 b128/K-tile/wave). Depth-3 stages, vmcnt(6)@pD.
#define STG(SM, sb, sh, st)                                                        \
  { const _Float16* g_ = (SM) ? Bg : Ag;                                           \
    const size_t r0_ = (SM) ? brow0 : arow0, r1_ = (SM) ? brow1 : arow1;           \
    const size_t h_  = (sh) ? ((SM) ? bh128 : ah128) : 0;                          \
    _Float16* l_ = ((SM) ? Bs : As) + (((sb) * 2 + (sh)) << 13);                   \
    gl_lds16(g_ + r0_ + h_ + (size_t)(st) * 64 + sg0 * 8, l_ + lo0);               \
    gl_lds16(g_ + r1_ + h_ + (size_t)(st) * 64 + sg1 * 8, l_ + lo1); }

#define LD_A(cb, mh, ks_)                                                          \
  { const _Float16* ah_ = As + (((cb) * 2 + (mh)) << 13);                          \
    ar[0][ks_] = *(const half8*)(ah_ + aoff[0] + koff[ks_]);                       \
    ar[1][ks_] = *(const half8*)(ah_ + aoff[1] + koff[ks_]);                       \
    ar[2][ks_] = *(const half8*)(ah_ + aoff[2] + koff[ks_]);                       \
    ar[3][ks_] = *(const half8*)(ah_ + aoff[3] + koff[ks_]); }

#define LD_B(cb, nh, ks_)                                                          \
  { const _Float16* bh_ = Bs + (((cb) * 2 + (nh)) << 13);                          \
    br[0][ks_] = *(const half8*)(bh_ + boff[0] + koff[ks_]);                       \
    br[1][ks_] = *(const half8*)(bh_ + boff[1] + koff[ks_]); }

#define M8(mh, nh, ks_)                                                            \
  __builtin_amdgcn_s_setprio(1);                                                   \
  _Pragma("unroll") for (int mi = 0; mi < 4; ++mi)                                 \
    _Pragma("unroll") for (int ni = 0; ni < 2; ++ni)                               \
      acc[(mh) * 4 + mi][(nh) * 2 + ni] =                                          \
          __builtin_amdgcn_mfma_f32_16x16x32_f16(                                  \
              ar[mi][ks_], br[ni][ks_], acc[(mh) * 4 + mi][(nh) * 2 + ni],         \
              0, 0, 0);                                                            \
  __builtin_amdgcn_s_setprio(0);

#define LGKM(n) asm volatile("s_waitcnt lgkmcnt(" #n ")" ::: "memory");            \
  __builtin_amdgcn_sched_barrier(0)

#define BARRIER __builtin_amdgcn_s_barrier(); asm volatile("" ::: "memory")

// quadrant (0,1); self-loads R0; stage early
#define PH_A(cb, ...)                                                              \
  __VA_ARGS__;                                                                     \
  LD_A(cb, 0, 0) LD_B(cb, 1, 0)                                                    \
  LD_A(cb, 0, 1) LD_B(cb, 1, 1)                                                    \
  LGKM(6); M8(0, 1, 0)                                                             \
  LD_B(cb, 0, 0)                                                                   \
  LGKM(2); M8(0, 1, 1)                                                             \
  BARRIER;

// quadrant (0,0)
#define PH_B(cb, ...)                                                              \
  __VA_ARGS__;                                                                     \
  LD_B(cb, 0, 1)                                                                   \
  LGKM(2); M8(0, 0, 0)                                                             \
  LD_A(cb, 1, 0)                                                                   \
  LGKM(4); M8(0, 0, 1)                                                             \
  BARRIER;

// quadrant (1,0); no stage
#define PH_C(cb)                                                                   \
  LD_A(cb, 1, 1)                                                                   \
  LGKM(4); M8(1, 0, 0)                                                             \
  LD_B(cb, 1, 0)                                                                   \
  LGKM(2); M8(1, 0, 1)                                                             \
  BARRIER;

// quadrant (1,1); boundary: no next-R0; vmcnt(6)
#define PH_D(cb, ...)                                                              \
  __VA_ARGS__;                                                                     \
  LD_B(cb, 1, 1)                                                                   \
  LGKM(2); M8(1, 1, 0)                                                             \
  LGKM(0); M8(1, 1, 1)                                                             \
  asm volatile("s_waitcnt vmcnt(6)" ::: "memory");                                 \
  __builtin_amdgcn_sched_barrier(0);                                               \
  BARRIER;

__device__ __forceinline__ void gemm8p(const _Float16* __restrict__ Ag,
                                       const _Float16* __restrict__ Bg,
                                       int lda, int ldb, int K,
                                       f32x4 acc[8][4],
                                       _Float16* As, _Float16* Bs) {
  const int tid = threadIdx.x;
  const int lane = tid & 63;
  const int w = tid >> 6;
  const int wm = w >> 2, wn = w & 3;
  const int lr = lane & 15, kl = lane >> 4;

  int aoff[4], boff[2], koff[2];
#pragma unroll
  for (int mi = 0; mi < 4; ++mi) aoff[mi] = (wm * 64 + mi * 16 + lr) * 64;
#pragma unroll
  for (int ni = 0; ni < 2; ++ni) boff[ni] = (wn * 32 + ni * 16 + lr) * 64;
#pragma unroll
  for (int ks = 0; ks < 2; ++ks) koff[ks] = ((ks * 4 + kl) ^ (lr & 7)) * 8;

  const int s0 = (w * 2 + 0) * 64 + lane, s1 = (w * 2 + 1) * 64 + lane;
  const int srow0 = s0 >> 3, srow1 = s1 >> 3;
  const int sg0 = (s0 & 7) ^ (srow0 & 7), sg1 = (s1 & 7) ^ (srow1 & 7);
  const int lo0 = (w * 2 + 0) * 512, lo1 = (w * 2 + 1) * 512;
  const size_t arow0 = (size_t)srow0 * lda, arow1 = (size_t)srow1 * lda;
  const size_t brow0 = (size_t)srow0 * ldb, brow1 = (size_t)srow1 * ldb;
  const size_t ah128 = (size_t)128 * lda, bh128 = (size_t)128 * ldb;

  const int NT = K >> 6, NITER = NT >> 1, TM = NT - 1;
  half8 ar[4][2], br[2][2];

  // prologue: t0 all 4 halves + t1.Ah0, t1.Bh0, t1.Ah1 (14 loads/lane)
  STG(0, 0, 0, 0); STG(1, 0, 0, 0);
  STG(0, 0, 1, 0); STG(1, 0, 1, 0);
  STG(0, 1, 0, 1); STG(1, 1, 0, 1);
  STG(0, 1, 1, 1);
  asm volatile("s_waitcnt vmcnt(6)" ::: "memory");  // t0 landed
  __builtin_amdgcn_sched_barrier(0);
  BARRIER;

  for (int it = 0; it < NITER; ++it) {
    const int tb = 2 * it + 1;
    const int tc = (2 * it + 2) & TM;  // wrap: harmless reload at the tail
    const int td = (2 * it + 3) & TM;
    // buf0 (tile 2it)
    PH_A(0, STG(1, 1, 1, tb))                     // tb.Bh1 -> buf1
    PH_B(0, STG(0, 0, 0, tc))                     // tc.Ah0 -> buf0
    PH_C(0)
    PH_D(0, STG(1, 0, 0, tc); STG(0, 0, 1, tc))   // tc.Bh0,Ah1 ; vmcnt(6)->tb landed
    // buf1 (tile 2it+1)
    PH_A(1, STG(1, 0, 1, tc))                     // tc.Bh1 -> buf0
    PH_B(1, STG(0, 1, 0, td))                     // td.Ah0 -> buf1
    PH_C(1)
    PH_D(1, STG(1, 1, 0, td); STG(0, 1, 1, td))   // td.Bh0,Ah1 ; vmcnt(6)->tc landed
  }
  asm volatile("s_waitcnt vmcnt(0)" ::: "memory");  // drain wrapped stages
}

#define GEMM_PROLOGUE()                                              \
  __shared__ __align__(16) unsigned char SMEM[131072];               \
  _Float16* As = (_Float16*)SMEM;                                    \
  _Float16* Bs = (_Float16*)(SMEM + 65536);                          \
  f32x4 acc[8][4];                                                   \
  _Pragma("unroll") for (int i_ = 0; i_ < 8; ++i_)                   \
      _Pragma("unroll") for (int j_ = 0; j_ < 4; ++j_)               \
          acc[i_][j_] = (f32x4){0.f, 0.f, 0.f, 0.f};

#define EPI_IDX()                                                    \
  const int tid = threadIdx.x, lane = tid & 63, w = tid >> 6;        \
  const int wm = w >> 2, wn = w & 3, lr = lane & 15, kl = lane >> 4; \
  (void)tid; (void)lane;

// ---------------------------------------------------------------- kernels
__global__ __launch_bounds__(512, 2) void proj_kernel(
    const _Float16* __restrict__ x16, const _Float16* __restrict__ Wb,
    _Float16* __restrict__ Qb, _Float16* __restrict__ Kb, _Float16* __restrict__ Vt,
    const float* __restrict__ bq, const float* __restrict__ bk,
    const float* __restrict__ bv, const float* __restrict__ alpha_p,
    const float* __restrict__ attn_bias) {
  GEMM_PROLOGUE();
  const int m0 = blockIdx.x * 256;
  const int n0 = blockIdx.y * 256;
  gemm8p(x16 + (size_t)m0 * DDIM, Wb + (size_t)n0 * DDIM, DDIM, DDIM, DDIM,
         acc, As, Bs);
  EPI_IDX();
  const int region = blockIdx.y >> 2;  // 0=Q 1=K 2=V
  const float alsc = alpha_p[0] * 0.03125f;  // alpha / sqrt(1024)
  __syncthreads();  // all waves' vmcnt(0) done -> LDS safe to reuse
  if (region == 2) {
    // V: frag rows are s-contiguous in Vt -> direct half4 stores
#pragma unroll
    for (int a = 0; a < 8; ++a) {
      const int row0 = m0 + (a >> 2) * 128 + wm * 64 + (a & 3) * 16 + kl * 4;
#pragma unroll
      for (int bi = 0; bi < 4; ++bi) {
        const int col = n0 + (bi >> 1) * 128 + wn * 32 + (bi & 1) * 16 + lr;
        const int d = col - 2048;
        const float bias = bv[d];
        const int bidx = row0 >> 11;
        const int sr = row0 & (T_SEQ - 1);
        half4 p;
#pragma unroll
        for (int r = 0; r < 4; ++r) p[r] = (_Float16)(acc[a][bi][r] + bias);
        *(half4*)&Vt[((size_t)bidx * DDIM + d) * T_SEQ + sr] = p;
      }
    }
  } else {
    // Q/K: per-wave LDS transpose (stride 56 f16), coalesced half8 stores
    _Float16* sc = (_Float16*)(SMEM + (size_t)w * 7168);
    _Float16* dst = (region == 0) ? Qb : Kb;
    const int coff = (region == 1) ? 1024 : 0;
#pragma unroll
    for (int mh = 0; mh < 2; ++mh)
#pragma unroll
      for (int nh = 0; nh < 2; ++nh) {
#pragma unroll
        for (int mi = 0; mi < 4; ++mi) {
          const int row_l = mi * 16 + kl * 4;
          const int s0g = (m0 + mh * 128 + wm * 64 + row_l) & (T_SEQ - 1);
#pragma unroll
          for (int ni = 0; ni < 2; ++ni) {
            const int col_l = ni * 16 + lr;
            const int colg = n0 + nh * 128 + wn * 32 + col_l;
            f32x4 v = acc[mh * 4 + mi][nh * 2 + ni];
            if (region == 0) {
              const float b = bq[colg];
#pragma unroll
              for (int r = 0; r < 4; ++r)
                sc[(row_l + r) * 56 + col_l] = (_Float16)(v[r] + b);
            } else {
              const int d = colg - 1024;
              const float b = bk[d];
              float4 ab = *(const float4*)&attn_bias[(size_t)d * T_SEQ + s0g];
              sc[(row_l + 0) * 56 + col_l] = (_Float16)((v[0] + b) * alsc + ab.x);
              sc[(row_l + 1) * 56 + col_l] = (_Float16)((v[1] + b) * alsc + ab.y);
              sc[(row_l + 2) * 56 + col_l] = (_Float16)((v[2] + b) * alsc + ab.z);
              sc[(row_l + 3) * 56 + col_l] = (_Float16)((v[3] + b) * alsc + ab.w);
            }
          }
        }
#pragma unroll
        for (int p = 0; p < 4; ++p) {
          const int row = p * 16 + (lane >> 2);
          const int c8 = (lane & 3) * 8;
          half8 hv = *(const half8*)&sc[row * 56 + c8];
          *(half8*)&dst[(size_t)(m0 + mh * 128 + wm * 64 + row) * DDIM +
                        n0 + nh * 128 + wn * 32 + c8 - coff] = hv;
        }
      }
  }
}

__global__ __launch_bounds__(512, 2) void gate_kernel(
    const _Float16* __restrict__ Qb, const _Float16* __restrict__ Wgb,
    const float* __restrict__ bg, float* __restrict__ gate_out) {
  GEMM_PROLOGUE();
  const int m0 = blockIdx.x * 256;
  const int n0 = blockIdx.y * 256;
  gemm8p(Qb + (size_t)m0 * DDIM, Wgb + (size_t)n0 * DDIM, DDIM, DDIM, DDIM,
         acc, As, Bs);
  EPI_IDX();
  __syncthreads();
  float* sc = (float*)(SMEM + (size_t)w * 9216);
#pragma unroll
  for (int mh = 0; mh < 2; ++mh)
#pragma unroll
    for (int nh = 0; nh < 2; ++nh) {
#pragma unroll
      for (int mi = 0; mi < 4; ++mi)
#pragma unroll
        for (int ni = 0; ni < 2; ++ni) {
          const int col_l = ni * 16 + lr;
          const float b = bg[n0 + nh * 128 + wn * 32 + col_l];
          f32x4 v = acc[mh * 4 + mi][nh * 2 + ni];
#pragma unroll
          for (int r = 0; r < 4; ++r)
            sc[(mi * 16 + kl * 4 + r) * 36 + col_l] =
                1.0f / (1.0f + __expf(-(v[r] + b)));
        }
#pragma unroll
      for (int p = 0; p < 8; ++p) {
        const int row = p * 8 + (lane >> 3);
        const int c4 = (lane & 7) * 4;
        f32x4 v = *(const f32x4*)&sc[row * 36 + c4];
        *(f32x4*)&gate_out[(size_t)(m0 + mh * 128 + wm * 64 + row) * DDIM +
                           n0 + nh * 128 + wn * 32 + c4] = v;
      }
    }
}

__global__ __launch_bounds__(512, 2) void scores_kernel(
    const _Float16* __restrict__ Qb, const _Float16* __restrict__ Kb,
    float* __restrict__ w_out) {
  GEMM_PROLOGUE();
  const int b = blockIdx.z;
  const int m0 = blockIdx.x * 256;
  const int n0 = blockIdx.y * 256;
  gemm8p(Qb + ((size_t)b * T_SEQ + m0) * DDIM,
         Kb + ((size_t)b * T_SEQ + n0) * DDIM, DDIM, DDIM, DDIM,
         acc, As, Bs);
  EPI_IDX();
  __syncthreads();
  float* wp = w_out + (size_t)b * T_SEQ * T_SEQ;
  float* sc = (float*)(SMEM + (size_t)w * 9216);
#pragma unroll
  for (int mh = 0; mh < 2; ++mh)
#pragma unroll
    for (int nh = 0; nh < 2; ++nh) {
#pragma unroll
      for (int mi = 0; mi < 4; ++mi)
#pragma unroll
        for (int ni = 0; ni < 2; ++ni) {
          f32x4 v = acc[mh * 4 + mi][nh * 2 + ni];
#pragma unroll
          for (int r = 0; r < 4; ++r)
            sc[(mi * 16 + kl * 4 + r) * 36 + ni * 16 + lr] = v[r];
        }
#pragma unroll
      for (int p = 0; p < 8; ++p) {
        const int row = p * 8 + (lane >> 3);
        const int c4 = (lane & 7) * 4;
        f32x4 v = *(const f32x4*)&sc[row * 36 + c4];
        *(f32x4*)&wp[(size_t)(m0 + mh * 128 + wm * 64 + row) * T_SEQ +
                     n0 + nh * 128 + wn * 32 + c4] = v;
      }
    }
}

// in-place fp32 row softmax over 2048, plus f16 copy for the PV GEMM
__global__ __launch_bounds__(256) void softmax_kernel(float* __restrict__ wmat,
                                                      _Float16* __restrict__ P16) {
  float* row = wmat + (size_t)blockIdx.x * T_SEQ;
  const int tid = threadIdx.x;
  float4 v0 = *(float4*)(row + tid * 4);
  float4 v1 = *(float4*)(row + 1024 + tid * 4);
  float m = fmaxf(fmaxf(fmaxf(v0.x, v0.y), fmaxf(v0.z, v0.w)),
                  fmaxf(fmaxf(v1.x, v1.y), fmaxf(v1.z, v1.w)));
#pragma unroll
  for (int off = 32; off > 0; off >>= 1) m = fmaxf(m, __shfl_xor(m, off));
  __shared__ float red[8];
  const int wv = tid >> 6, ln = tid & 63;
  if (ln == 0) red[wv] = m;
  __syncthreads();
  m = fmaxf(fmaxf(red[0], red[1]), fmaxf(red[2], red[3]));
  v0.x = __expf(v0.x - m); v0.y = __expf(v0.y - m);
  v0.z = __expf(v0.z - m); v0.w = __expf(v0.w - m);
  v1.x = __expf(v1.x - m); v1.y = __expf(v1.y - m);
  v1.z = __expf(v1.z - m); v1.w = __expf(v1.w - m);
  float s = v0.x + v0.y + v0.z + v0.w + v1.x + v1.y + v1.z + v1.w;
#pragma unroll
  for (int off = 32; off > 0; off >>= 1) s += __shfl_xor(s, off);
  if (ln == 0) red[4 + wv] = s;
  __syncthreads();
  const float inv = 1.0f / (red[4] + red[5] + red[6] + red[7]);
  v0.x *= inv; v0.y *= inv; v0.z *= inv; v0.w *= inv;
  v1.x *= inv; v1.y *= inv; v1.z *= inv; v1.w *= inv;
  *(float4*)(row + tid * 4) = v0;
  *(float4*)(row + 1024 + tid * 4) = v1;
  _Float16* prow = P16 + (size_t)blockIdx.x * T_SEQ;
  half4 h0, h1;
  h0[0] = (_Float16)v0.x; h0[1] = (_Float16)v0.y; h0[2] = (_Float16)v0.z; h0[3] = (_Float16)v0.w;
  h1[0] = (_Float16)v1.x; h1[1] = (_Float16)v1.y; h1[2] = (_Float16)v1.z; h1[3] = (_Float16)v1.w;
  *(half4*)(prow + tid * 4) = h0;
  *(half4*)(prow + 1024 + tid * 4) = h1;
}

// attn_output[b] = (P16_b @ V_b) * gate ; gate parked in `out` (exact aliasing).
__global__ __launch_bounds__(512, 2) void pv_kernel(
    const _Float16* __restrict__ P16, const _Float16* __restrict__ Vt,
    float* __restrict__ out) {
  GEMM_PROLOGUE();
  const int b = blockIdx.z;
  const int m0 = blockIdx.x * 256;
  const int n0 = blockIdx.y * 256;
  gemm8p(P16 + ((size_t)b * T_SEQ + m0) * T_SEQ,
         Vt + (size_t)b * DDIM * T_SEQ + (size_t)n0 * T_SEQ,
         T_SEQ, T_SEQ, T_SEQ, acc, As, Bs);
  EPI_IDX();
  __syncthreads();
  float* sc = (float*)(SMEM + (size_t)w * 9216);
#pragma unroll
  for (int mh = 0; mh < 2; ++mh)
#pragma unroll
    for (int nh = 0; nh < 2; ++nh) {
#pragma unroll
      for (int mi = 0; mi < 4; ++mi)
#pragma unroll
        for (int ni = 0; ni < 2; ++ni) {
          f32x4 v = acc[mh * 4 + mi][nh * 2 + ni];
#pragma unroll
          for (int r = 0; r < 4; ++r)
            sc[(mi * 16 + kl * 4 + r) * 36 + ni * 16 + lr] = v[r];
        }
#pragma unroll
      for (int p = 0; p < 8; ++p) {
        const int row = p * 8 + (lane >> 3);
        const int c4 = (lane & 7) * 4;
        f32x4 v = *(const f32x4*)&sc[row * 36 + c4];
        float* op = &out[(size_t)((size_t)b * T_SEQ + m0 + mh * 128 + wm * 64 + row) * DDIM +
                         n0 + nh * 128 + wn * 32 + c4];
        f32x4 g = *(const f32x4*)op;  // gate parked here by gate_kernel
        *(f32x4*)op = v * g;
      }
    }
}

// ---------------------------------------------------------------- launch
extern "C" void kernel_launch(void* const* d_in, const int* in_sizes, int n_in,
                              void* d_out, int out_size, void* d_ws, size_t ws_size,
                              hipStream_t stream) {
  const float* x         = (const float*)d_in[0];
  const float* Wq        = (const float*)d_in[1];
  const float* bq        = (const float*)d_in[2];
  const float* Wk        = (const float*)d_in[3];
  const float* bk        = (const float*)d_in[4];
  const float* Wv        = (const float*)d_in[5];
  const float* bv        = (const float*)d_in[6];
  const float* Wg        = (const float*)d_in[7];
  const float* bg        = (const float*)d_in[8];
  const float* alpha     = (const float*)d_in[9];
  const float* attn_bias = (const float*)d_in[10];

  float* out   = (float*)d_out;
  float* out_w = out + (size_t)BATCH * T_SEQ * DDIM;  // attn_weights region

  // ws (f16 units): Wb[0,4M) | Qb[4M,20M) | Kb[20M,36M) | Vt[36M,52M) = 104 MiB
  _Float16* Wb  = (_Float16*)d_ws;
  _Float16* Qb  = Wb + ((size_t)4 << 20);
  _Float16* Kb  = Qb + ((size_t)16 << 20);
  _Float16* Vt  = Kb + ((size_t)16 << 20);
  _Float16* P16 = Qb;  // 64 MiB alias (Qb+Kb dead after scores)
  _Float16* x16 = (_Float16*)out_w;  // parked in attn_weights region

  cvt_all<<<10240, 256, 0, stream>>>(Wq, Wk, Wv, Wg, x, Wb, x16);
  proj_kernel<<<dim3(64, 12), 512, 0, stream>>>(x16, Wb, Qb, Kb, Vt, bq, bk, bv, alpha, attn_bias);
  gate_kernel<<<dim3(64, 4), 512, 0, stream>>>(Qb, Wb + (3 << 20), bg, out);
  scores_kernel<<<dim3(8, 8, 8), 512, 0, stream>>>(Qb, Kb, out_w);
  softmax_kernel<<<16384, 256, 0, stream>>>(out_w, P16);
  pv_kernel<<<dim3(8, 4, 8), 512, 0, stream>>>(P16, Vt, out);
}

// Round 8
// 379.188 us; speedup vs baseline: 1.1168x; 1.0060x over previous
//
#include <hip/hip_runtime.h>
#include <stdint.h>

#define T_SEQ 2048
#define DDIM  1024
#define BATCH 8

using f32x4 = __attribute__((ext_vector_type(4))) float;
using half8 = __attribute__((ext_vector_type(8))) _Float16;
using half4 = __attribute__((ext_vector_type(4))) _Float16;

// async global->LDS, 16B/lane; LDS dest = wave-uniform base + lane*16
__device__ __forceinline__ void gl_lds16(const _Float16* g, _Float16* l) {
  __builtin_amdgcn_global_load_lds((const __attribute__((address_space(1))) void*)g,
                                   (__attribute__((address_space(3))) void*)l,
                                   16, 0, 0);
}

// ---------------------------------------------------------------- converts
__global__ __launch_bounds__(256) void cvt_all(
    const float* __restrict__ Wq, const float* __restrict__ Wk,
    const float* __restrict__ Wv, const float* __restrict__ Wg,
    const float* __restrict__ x, _Float16* __restrict__ Wb,
    _Float16* __restrict__ x16) {
  const size_t i = ((size_t)blockIdx.x * 256 + threadIdx.x) * 8;
  const float* s; _Float16* d; size_t off;
  if (i < (size_t)(1 << 20))      { s = Wq; d = Wb;             off = i; }
  else if (i < (size_t)(2 << 20)) { s = Wk; d = Wb + (1 << 20); off = i - (1 << 20); }
  else if (i < (size_t)(3 << 20)) { s = Wv; d = Wb + (2 << 20); off = i - (2 << 20); }
  else if (i < (size_t)(4 << 20)) { s = Wg; d = Wb + (3 << 20); off = i - (3 << 20); }
  else                            { s = x;  d = x16;            off = i - (4 << 20); }
  float4 a = *(const float4*)(s + off);
  float4 b = *(const float4*)(s + off + 4);
  half8 h;
  h[0] = (_Float16)a.x; h[1] = (_Float16)a.y; h[2] = (_Float16)a.z; h[3] = (_Float16)a.w;
  h[4] = (_Float16)b.x; h[5] = (_Float16)b.y; h[6] = (_Float16)b.z; h[7] = (_Float16)b.w;
  *(half8*)(d + off) = h;
}

// ---------------------------------------------------------------- 256^2 GEMM core
// ONE barrier per K-tile: during tile t all reads hit buf(t&1), all stages
// target buf^1 -> no intra-tile LDS hazard. Boundary = vmcnt(0) (own stages
// for t+1 landed; front-loaded ~2 quadrants earlier) + s_barrier (all readers
// of buf done before next tile's stages into it are issued). Counted-lgkm
// chain (6,2/2,4/4,2/2,0) identical to r7-verified. Waves free-run within a
// tile -> reads overlap SIMD-mate MFMAs.
#define STG(SM, sb, sh, st)                                                        \
  { const _Float16* g_ = (SM) ? Bg : Ag;                                           \
    const size_t r0_ = (SM) ? brow0 : arow0, r1_ = (SM) ? brow1 : arow1;           \
    const size_t h_  = (sh) ? ((SM) ? bh128 : ah128) : 0;                          \
    _Float16* l_ = ((SM) ? Bs : As) + (((sb) * 2 + (sh)) << 13);                   \
    gl_lds16(g_ + r0_ + h_ + (size_t)(st) * 64 + sg0 * 8, l_ + lo0);               \
    gl_lds16(g_ + r1_ + h_ + (size_t)(st) * 64 + sg1 * 8, l_ + lo1); }

#define LD_A(cb, mh, ks_)                                                          \
  { const _Float16* ah_ = As + (((cb) * 2 + (mh)) << 13);                          \
    ar[0][ks_] = *(const half8*)(ah_ + aoff[0] + koff[ks_]);                       \
    ar[1][ks_] = *(const half8*)(ah_ + aoff[1] + koff[ks_]);                       \
    ar[2][ks_] = *(const half8*)(ah_ + aoff[2] + koff[ks_]);                       \
    ar[3][ks_] = *(const half8*)(ah_ + aoff[3] + koff[ks_]); }

#define LD_B(cb, nh, ks_)                                                          \
  { const _Float16* bh_ = Bs + (((cb) * 2 + (nh)) << 13);                          \
    br[0][ks_] = *(const half8*)(bh_ + boff[0] + koff[ks_]);                       \
    br[1][ks_] = *(const half8*)(bh_ + boff[1] + koff[ks_]); }

#define M8(mh, nh, ks_)                                                            \
  __builtin_amdgcn_s_setprio(1);                                                   \
  _Pragma("unroll") for (int mi = 0; mi < 4; ++mi)                                 \
    _Pragma("unroll") for (int ni = 0; ni < 2; ++ni)                               \
      acc[(mh) * 4 + mi][(nh) * 2 + ni] =                                          \
          __builtin_amdgcn_mfma_f32_16x16x32_f16(                                  \
              ar[mi][ks_], br[ni][ks_], acc[(mh) * 4 + mi][(nh) * 2 + ni],         \
              0, 0, 0);                                                            \
  __builtin_amdgcn_s_setprio(0);

#define LGKM(n) asm volatile("s_waitcnt lgkmcnt(" #n ")" ::: "memory");            \
  __builtin_amdgcn_sched_barrier(0)

#define BARRIER __builtin_amdgcn_s_barrier(); asm volatile("" ::: "memory")

// one K-tile: quadrants (0,1),(0,0),(1,0),(1,1); stages front-loaded
#define TILE(cb, nb, tn)                                                           \
  STG(0, nb, 0, tn); STG(1, nb, 0, tn);           /* next h0 early */              \
  LD_A(cb, 0, 0) LD_B(cb, 1, 0)                                                    \
  LD_A(cb, 0, 1) LD_B(cb, 1, 1)                                                    \
  LGKM(6); M8(0, 1, 0)                                                             \
  LD_B(cb, 0, 0)                                                                   \
  LGKM(2); M8(0, 1, 1)                                                             \
  STG(0, nb, 1, tn); STG(1, nb, 1, tn);           /* next h1 mid-tile */           \
  LD_B(cb, 0, 1)                                                                   \
  LGKM(2); M8(0, 0, 0)                                                             \
  LD_A(cb, 1, 0)                                                                   \
  LGKM(4); M8(0, 0, 1)                                                             \
  LD_A(cb, 1, 1)                                                                   \
  LGKM(4); M8(1, 0, 0)                                                             \
  LD_B(cb, 1, 0)                                                                   \
  LGKM(2); M8(1, 0, 1)                                                             \
  LD_B(cb, 1, 1)                                                                   \
  LGKM(2); M8(1, 1, 0)                                                             \
  LGKM(0); M8(1, 1, 1)                                                             \
  asm volatile("s_waitcnt vmcnt(0)" ::: "memory");  /* t+1 landed */               \
  __builtin_amdgcn_sched_barrier(0);                                               \
  BARRIER;

__device__ __forceinline__ void gemm8p(const _Float16* __restrict__ Ag,
                                       const _Float16* __restrict__ Bg,
                                       int lda, int ldb, int K,
                                       f32x4 acc[8][4],
                                       _Float16* As, _Float16* Bs) {
  const int tid = threadIdx.x;
  const int lane = tid & 63;
  const int w = tid >> 6;
  const int wm = w >> 2, wn = w & 3;
  const int lr = lane & 15, kl = lane >> 4;

  int aoff[4], boff[2], koff[2];
#pragma unroll
  for (int mi = 0; mi < 4; ++mi) aoff[mi] = (wm * 64 + mi * 16 + lr) * 64;
#pragma unroll
  for (int ni = 0; ni < 2; ++ni) boff[ni] = (wn * 32 + ni * 16 + lr) * 64;
#pragma unroll
  for (int ks = 0; ks < 2; ++ks) koff[ks] = ((ks * 4 + kl) ^ (lr & 7)) * 8;

  const int s0 = (w * 2 + 0) * 64 + lane, s1 = (w * 2 + 1) * 64 + lane;
  const int srow0 = s0 >> 3, srow1 = s1 >> 3;
  const int sg0 = (s0 & 7) ^ (srow0 & 7), sg1 = (s1 & 7) ^ (srow1 & 7);
  const int lo0 = (w * 2 + 0) * 512, lo1 = (w * 2 + 1) * 512;
  const size_t arow0 = (size_t)srow0 * lda, arow1 = (size_t)srow1 * lda;
  const size_t brow0 = (size_t)srow0 * ldb, brow1 = (size_t)srow1 * ldb;
  const size_t ah128 = (size_t)128 * lda, bh128 = (size_t)128 * ldb;

  const int NT = K >> 6, NITER = NT >> 1, TM = NT - 1;
  half8 ar[4][2], br[2][2];

  // prologue: stage tile 0 into buf0 (8 loads/lane), wait, publish
  STG(0, 0, 0, 0); STG(1, 0, 0, 0);
  STG(0, 0, 1, 0); STG(1, 0, 1, 0);
  asm volatile("s_waitcnt vmcnt(0)" ::: "memory");
  __builtin_amdgcn_sched_barrier(0);
  BARRIER;

  for (int it = 0; it < NITER; ++it) {
    const int ta = (2 * it + 1);        // staged during even tile
    const int tb = (2 * it + 2) & TM;   // staged during odd tile (wraps at tail)
    TILE(0, 1, ta)
    TILE(1, 0, tb)
  }
  asm volatile("s_waitcnt vmcnt(0)" ::: "memory");  // safety (already drained)
}

#define GEMM_PROLOGUE()                                              \
  __shared__ __align__(16) unsigned char SMEM[131072];               \
  _Float16* As = (_Float16*)SMEM;                                    \
  _Float16* Bs = (_Float16*)(SMEM + 65536);                          \
  f32x4 acc[8][4];                                                   \
  _Pragma("unroll") for (int i_ = 0; i_ < 8; ++i_)                   \
      _Pragma("unroll") for (int j_ = 0; j_ < 4; ++j_)               \
          acc[i_][j_] = (f32x4){0.f, 0.f, 0.f, 0.f};

#define EPI_IDX()                                                    \
  const int tid = threadIdx.x, lane = tid & 63, w = tid >> 6;        \
  const int wm = w >> 2, wn = w & 3, lr = lane & 15, kl = lane >> 4; \
  (void)tid; (void)lane;

// ---------------------------------------------------------------- kernels
__global__ __launch_bounds__(512, 2) void proj_kernel(
    const _Float16* __restrict__ x16, const _Float16* __restrict__ Wb,
    _Float16* __restrict__ Qb, _Float16* __restrict__ Kb, _Float16* __restrict__ Vt,
    const float* __restrict__ bq, const float* __restrict__ bk,
    const float* __restrict__ bv, const float* __restrict__ alpha_p,
    const float* __restrict__ attn_bias) {
  GEMM_PROLOGUE();
  const int m0 = blockIdx.x * 256;
  const int n0 = blockIdx.y * 256;
  gemm8p(x16 + (size_t)m0 * DDIM, Wb + (size_t)n0 * DDIM, DDIM, DDIM, DDIM,
         acc, As, Bs);
  EPI_IDX();
  const int region = blockIdx.y >> 2;  // 0=Q 1=K 2=V
  const float alsc = alpha_p[0] * 0.03125f;  // alpha / sqrt(1024)
  __syncthreads();  // all waves drained (vmcnt0) -> LDS safe to reuse
  if (region == 2) {
    // V: frag rows are s-contiguous in Vt -> direct half4 stores
#pragma unroll
    for (int a = 0; a < 8; ++a) {
      const int row0 = m0 + (a >> 2) * 128 + wm * 64 + (a & 3) * 16 + kl * 4;
#pragma unroll
      for (int bi = 0; bi < 4; ++bi) {
        const int col = n0 + (bi >> 1) * 128 + wn * 32 + (bi & 1) * 16 + lr;
        const int d = col - 2048;
        const float bias = bv[d];
        const int bidx = row0 >> 11;
        const int sr = row0 & (T_SEQ - 1);
        half4 p;
#pragma unroll
        for (int r = 0; r < 4; ++r) p[r] = (_Float16)(acc[a][bi][r] + bias);
        *(half4*)&Vt[((size_t)bidx * DDIM + d) * T_SEQ + sr] = p;
      }
    }
  } else {
    // Q/K: per-wave LDS transpose (stride 56 f16), coalesced half8 stores
    _Float16* sc = (_Float16*)(SMEM + (size_t)w * 7168);
    _Float16* dst = (region == 0) ? Qb : Kb;
    const int coff = (region == 1) ? 1024 : 0;
#pragma unroll
    for (int mh = 0; mh < 2; ++mh)
#pragma unroll
      for (int nh = 0; nh < 2; ++nh) {
#pragma unroll
        for (int mi = 0; mi < 4; ++mi) {
          const int row_l = mi * 16 + kl * 4;
          const int s0g = (m0 + mh * 128 + wm * 64 + row_l) & (T_SEQ - 1);
#pragma unroll
          for (int ni = 0; ni < 2; ++ni) {
            const int col_l = ni * 16 + lr;
            const int colg = n0 + nh * 128 + wn * 32 + col_l;
            f32x4 v = acc[mh * 4 + mi][nh * 2 + ni];
            if (region == 0) {
              const float b = bq[colg];
#pragma unroll
              for (int r = 0; r < 4; ++r)
                sc[(row_l + r) * 56 + col_l] = (_Float16)(v[r] + b);
            } else {
              const int d = colg - 1024;
              const float b = bk[d];
              float4 ab = *(const float4*)&attn_bias[(size_t)d * T_SEQ + s0g];
              sc[(row_l + 0) * 56 + col_l] = (_Float16)((v[0] + b) * alsc + ab.x);
              sc[(row_l + 1) * 56 + col_l] = (_Float16)((v[1] + b) * alsc + ab.y);
              sc[(row_l + 2) * 56 + col_l] = (_Float16)((v[2] + b) * alsc + ab.z);
              sc[(row_l + 3) * 56 + col_l] = (_Float16)((v[3] + b) * alsc + ab.w);
            }
          }
        }
#pragma unroll
        for (int p = 0; p < 4; ++p) {
          const int row = p * 16 + (lane >> 2);
          const int c8 = (lane & 3) * 8;
          half8 hv = *(const half8*)&sc[row * 56 + c8];
          *(half8*)&dst[(size_t)(m0 + mh * 128 + wm * 64 + row) * DDIM +
                        n0 + nh * 128 + wn * 32 + c8 - coff] = hv;
        }
      }
  }
}

__global__ __launch_bounds__(512, 2) void gate_kernel(
    const _Float16* __restrict__ Qb, const _Float16* __restrict__ Wgb,
    const float* __restrict__ bg, float* __restrict__ gate_out) {
  GEMM_PROLOGUE();
  const int m0 = blockIdx.x * 256;
  const int n0 = blockIdx.y * 256;
  gemm8p(Qb + (size_t)m0 * DDIM, Wgb + (size_t)n0 * DDIM, DDIM, DDIM, DDIM,
         acc, As, Bs);
  EPI_IDX();
  __syncthreads();
  float* sc = (float*)(SMEM + (size_t)w * 9216);
#pragma unroll
  for (int mh = 0; mh < 2; ++mh)
#pragma unroll
    for (int nh = 0; nh < 2; ++nh) {
#pragma unroll
      for (int mi = 0; mi < 4; ++mi)
#pragma unroll
        for (int ni = 0; ni < 2; ++ni) {
          const int col_l = ni * 16 + lr;
          const float b = bg[n0 + nh * 128 + wn * 32 + col_l];
          f32x4 v = acc[mh * 4 + mi][nh * 2 + ni];
#pragma unroll
          for (int r = 0; r < 4; ++r)
            sc[(mi * 16 + kl * 4 + r) * 36 + col_l] =
                1.0f / (1.0f + __expf(-(v[r] + b)));
        }
#pragma unroll
      for (int p = 0; p < 8; ++p) {
        const int row = p * 8 + (lane >> 3);
        const int c4 = (lane & 7) * 4;
        f32x4 v = *(const f32x4*)&sc[row * 36 + c4];
        *(f32x4*)&gate_out[(size_t)(m0 + mh * 128 + wm * 64 + row) * DDIM +
                           n0 + nh * 128 + wn * 32 + c4] = v;
      }
    }
}

__global__ __launch_bounds__(512, 2) void scores_kernel(
    const _Float16* __restrict__ Qb, const _Float16* __restrict__ Kb,
    float* __restrict__ w_out) {
  GEMM_PROLOGUE();
  const int b = blockIdx.z;
  const int m0 = blockIdx.x * 256;
  const int n0 = blockIdx.y * 256;
  gemm8p(Qb + ((size_t)b * T_SEQ + m0) * DDIM,
         Kb + ((size_t)b * T_SEQ + n0) * DDIM, DDIM, DDIM, DDIM,
         acc, As, Bs);
  EPI_IDX();
  __syncthreads();
  float* wp = w_out + (size_t)b * T_SEQ * T_SEQ;
  float* sc = (float*)(SMEM + (size_t)w * 9216);
#pragma unroll
  for (int mh = 0; mh < 2; ++mh)
#pragma unroll
    for (int nh = 0; nh < 2; ++nh) {
#pragma unroll
      for (int mi = 0; mi < 4; ++mi)
#pragma unroll
        for (int ni = 0; ni < 2; ++ni) {
          f32x4 v = acc[mh * 4 + mi][nh * 2 + ni];
#pragma unroll
          for (int r = 0; r < 4; ++r)
            sc[(mi * 16 + kl * 4 + r) * 36 + ni * 16 + lr] = v[r];
        }
#pragma unroll
      for (int p = 0; p < 8; ++p) {
        const int row = p * 8 + (lane >> 3);
        const int c4 = (lane & 7) * 4;
        f32x4 v = *(const f32x4*)&sc[row * 36 + c4];
        *(f32x4*)&wp[(size_t)(m0 + mh * 128 + wm * 64 + row) * T_SEQ +
                     n0 + nh * 128 + wn * 32 + c4] = v;
      }
    }
}

// in-place fp32 row softmax over 2048, plus f16 copy for the PV GEMM
__global__ __launch_bounds__(256) void softmax_kernel(float* __restrict__ wmat,
                                                      _Float16* __restrict__ P16) {
  float* row = wmat + (size_t)blockIdx.x * T_SEQ;
  const int tid = threadIdx.x;
  float4 v0 = *(float4*)(row + tid * 4);
  float4 v1 = *(float4*)(row + 1024 + tid * 4);
  float m = fmaxf(fmaxf(fmaxf(v0.x, v0.y), fmaxf(v0.z, v0.w)),
                  fmaxf(fmaxf(v1.x, v1.y), fmaxf(v1.z, v1.w)));
#pragma unroll
  for (int off = 32; off > 0; off >>= 1) m = fmaxf(m, __shfl_xor(m, off));
  __shared__ float red[8];
  const int wv = tid >> 6, ln = tid & 63;
  if (ln == 0) red[wv] = m;
  __syncthreads();
  m = fmaxf(fmaxf(red[0], red[1]), fmaxf(red[2], red[3]));
  v0.x = __expf(v0.x - m); v0.y = __expf(v0.y - m);
  v0.z = __expf(v0.z - m); v0.w = __expf(v0.w - m);
  v1.x = __expf(v1.x - m); v1.y = __expf(v1.y - m);
  v1.z = __expf(v1.z - m); v1.w = __expf(v1.w - m);
  float s = v0.x + v0.y + v0.z + v0.w + v1.x + v1.y + v1.z + v1.w;
#pragma unroll
  for (int off = 32; off > 0; off >>= 1) s += __shfl_xor(s, off);
  if (ln == 0) red[4 + wv] = s;
  __syncthreads();
  const float inv = 1.0f / (red[4] + red[5] + red[6] + red[7]);
  v0.x *= inv; v0.y *= inv; v0.z *= inv; v0.w *= inv;
  v1.x *= inv; v1.y *= inv; v1.z *= inv; v1.w *= inv;
  *(float4*)(row + tid * 4) = v0;
  *(float4*)(row + 1024 + tid * 4) = v1;
  _Float16* prow = P16 + (size_t)blockIdx.x * T_SEQ;
  half4 h0, h1;
  h0[0] = (_Float16)v0.x; h0[1] = (_Float16)v0.y; h0[2] = (_Float16)v0.z; h0[3] = (_Float16)v0.w;
  h1[0] = (_Float16)v1.x; h1[1] = (_Float16)v1.y; h1[2] = (_Float16)v1.z; h1[3] = (_Float16)v1.w;
  *(half4*)(prow + tid * 4) = h0;
  *(half4*)(prow + 1024 + tid * 4) = h1;
}

// attn_output[b] = (P16_b @ V_b) * gate ; gate parked in `out` (exact aliasing).
__global__ __launch_bounds__(512, 2) void pv_kernel(
    const _Float16* __restrict__ P16, const _Float16* __restrict__ Vt,
    float* __restrict__ out) {
  GEMM_PROLOGUE();
  const int b = blockIdx.z;
  const int m0 = blockIdx.x * 256;
  const int n0 = blockIdx.y * 256;
  gemm8p(P16 + ((size_t)b * T_SEQ + m0) * T_SEQ,
         Vt + (size_t)b * DDIM * T_SEQ + (size_t)n0 * T_SEQ,
         T_SEQ, T_SEQ, T_SEQ, acc, As, Bs);
  EPI_IDX();
  __syncthreads();
  float* sc = (float*)(SMEM + (size_t)w * 9216);
#pragma unroll
  for (int mh = 0; mh < 2; ++mh)
#pragma unroll
    for (int nh = 0; nh < 2; ++nh) {
#pragma unroll
      for (int mi = 0; mi < 4; ++mi)
#pragma unroll
        for (int ni = 0; ni < 2; ++ni) {
          f32x4 v = acc[mh * 4 + mi][nh * 2 + ni];
#pragma unroll
          for (int r = 0; r < 4; ++r)
            sc[(mi * 16 + kl * 4 + r) * 36 + ni * 16 + lr] = v[r];
        }
#pragma unroll
      for (int p = 0; p < 8; ++p) {
        const int row = p * 8 + (lane >> 3);
        const int c4 = (lane & 7) * 4;
        f32x4 v = *(const f32x4*)&sc[row * 36 + c4];
        float* op = &out[(size_t)((size_t)b * T_SEQ + m0 + mh * 128 + wm * 64 + row) * DDIM +
                         n0 + nh * 128 + wn * 32 + c4];
        f32x4 g = *(const f32x4*)op;  // gate parked here by gate_kernel
        *(f32x4*)op = v * g;
      }
    }
}

// ---------------------------------------------------------------- launch
extern "C" void kernel_launch(void* const* d_in, const int* in_sizes, int n_in,
                              void* d_out, int out_size, void* d_ws, size_t ws_size,
                              hipStream_t stream) {
  const float* x         = (const float*)d_in[0];
  const float* Wq        = (const float*)d_in[1];
  const float* bq        = (const float*)d_in[2];
  const float* Wk        = (const float*)d_in[3];
  const float* bk        = (const float*)d_in[4];
  const float* Wv        = (const float*)d_in[5];
  const float* bv        = (const float*)d_in[6];
  const float* Wg        = (const float*)d_in[7];
  const float* bg        = (const float*)d_in[8];
  const float* alpha     = (const float*)d_in[9];
  const float* attn_bias = (const float*)d_in[10];

  float* out   = (float*)d_out;
  float* out_w = out + (size_t)BATCH * T_SEQ * DDIM;  // attn_weights region

  // ws (f16 units): Wb[0,4M) | Qb[4M,20M) | Kb[20M,36M) | Vt[36M,52M) = 104 MiB
  _Float16* Wb  = (_Float16*)d_ws;
  _Float16* Qb  = Wb + ((size_t)4 << 20);
  _Float16* Kb  = Qb + ((size_t)16 << 20);
  _Float16* Vt  = Kb + ((size_t)16 << 20);
  _Float16* P16 = Qb;  // 64 MiB alias (Qb+Kb dead after scores)
  _Float16* x16 = (_Float16*)out_w;  // parked in attn_weights region

  cvt_all<<<10240, 256, 0, stream>>>(Wq, Wk, Wv, Wg, x, Wb, x16);
  proj_kernel<<<dim3(64, 12), 512, 0, stream>>>(x16, Wb, Qb, Kb, Vt, bq, bk, bv, alpha, attn_bias);
  gate_kernel<<<dim3(64, 4), 512, 0, stream>>>(Qb, Wb + (3 << 20), bg, out);
  scores_kernel<<<dim3(8, 8, 8), 512, 0, stream>>>(Qb, Kb, out_w);
  softmax_kernel<<<16384, 256, 0, stream>>>(out_w, P16);
  pv_kernel<<<dim3(8, 4, 8), 512, 0, stream>>>(P16, Vt, out);
}